// Round 13
// baseline (6892.884 us; speedup 1.0000x reference)
//
#include <hip/hip_runtime.h>
#include <stdint.h>

// AutoregressiveRAM: 4095 serial steps of an 8192-neuron weightless NN.
// R13 = R2 champion skeleton (16 blocks x 512 thr, two barriers, L2 table
// lookup, out-store-then-publish) with the poll SAMPLING MECHANISM replaced:
//   ASYNC LDS-MEDIATED POLLING. Pollers stream mailbox samples into LDS
//   scratch via global_load_lds (dest = LDS, NOT compiler VGPRs -> loads
//   abandoned at loop exit are SOUND, unlike R7), paced by s_waitcnt
//   vmcnt(8) (~150cy cadence vs ~900cy blocking-spin cadence), checking
//   freshly-landed values with volatile ds_reads. Detection ~= phase(150)
//   + RTT + ds_read instead of phase(~RTT) + RTT.
//   TORN-READ SAFETY: tags are DATA-ENTANGLED: hi = (s+1)*K ^ lo (K odd).
//   Any generation-mix of (lo,hi) fails (hi^lo)==i*K unless data identical.
//   Stale cache hits can only match if they carry the wanted generation's
//   exact data -> correct by definition. Memset-0 mailbox never matches
//   (i*K != 0 for 1<=i<2^32 with K odd).
//   FAIL-SAFE: async timeout (AFUSE) sets sticky s_bad -> block permanently
//   degrades to the R2-proven blocking spin on the SAME words (same checks).
//   Fallback timeout poisons -> visible test failure. Never silent.
//
// Mailbox: [2 slots][128 pairs][2 x 8B words]; wave w of block b owns pair
// b*8+w. Publish = two 8B agent-scope atomic stores (champion-proven path).
// Pollers t<128 each own one 16B pair (incl. own block's: same max-visibility
// as remote since publishes are ~simultaneous; replaces champion's LDS
// self-write). Overwrite safety: slot reuse at step i+2 gated by iter-(i+1)
// poll success + two barriers (R2 proof, unchanged).

#define BITS   8192
#define NBT    10
#define NBLK   16
#define TPB    512
#define NPB    (BITS / NBLK)   // 512 neurons per block (1 per thread)
#define SWORDS 256             // 8192 state bits / 32
#define WPB    (NPB / 32)      // 16 state words owned per block
#define NPAIR  128             // 16B mailbox pairs per slot
#define KMUL   2654435761u     // odd multiplier for entangled tags
#define AFUSE  (1 << 12)       // async samples before sticky degrade
#define BFUSE  (1 << 14)       // blocking-spin samples before poison

typedef unsigned long long u64;
typedef uint32_t u32;

__global__ void pack_kernel(const float* __restrict__ tm, u32* __restrict__ packed) {
    // 8192*1024 floats -> 262144 packed u32 words. One float per thread.
    int tid = blockIdx.x * blockDim.x + threadIdx.x;
    float v = tm[tid];
    u64 m = __ballot(v > 0.5f);
    int lane = tid & 63;
    if ((lane & 31) == 0) {
        packed[tid >> 5] = (lane == 0) ? (u32)m : (u32)(m >> 32);
    }
}

__device__ __forceinline__ u64 mkword(u32 lo, u32 tag) {
    return ((u64)(tag ^ lo) << 32) | lo;     // hi = tag ^ lo (entangled)
}

__global__ __launch_bounds__(TPB) void ram_step_kernel(
    const int* __restrict__ conn,        // [8192][10]
    const float* __restrict__ init_mem,  // [8192][16]
    const u32* __restrict__ packedT,     // [8192][32]
    u64* __restrict__ pairs,             // [2][NPAIR][2] tagged 8B words
    float* __restrict__ out,             // [length][8192]
    int length)
{
    const int b = blockIdx.x;
    const int t = threadIdx.x;
    const int lane = t & 63;
    const int n = b * NPB + t;           // this thread's neuron

    __shared__ u32 st[SWORDS + 1];              // state + pos-bits word
    __shared__ volatile u32 scr[2][NPAIR][4];   // async landing zone (4KB)
    __shared__ int s_bad;                       // sticky: async path broken

    if (t == 0) s_bad = 0;

    // Connections are static: keep in registers for the whole run.
    int c[NBT];
#pragma unroll
    for (int j = 0; j < NBT; ++j) c[j] = conn[n * NBT + j];

    // ---- step 0: pos bits of 0 are all zero -> addr 0 -> initial_memory[:,0]
    float v0 = init_mem[n << 4];
    out[n] = v0;
    int bit = (v0 > 0.5f) ? 1 : 0;
    u64 m = __ballot(bit);
    const int gw = b * WPB + (t >> 6) * 2;  // this wave's global word base
    const int gp = gw >> 1;                 // this wave's mailbox pair
    if (lane == 0) {
        __hip_atomic_store(&pairs[gp * 2],     mkword((u32)m, 1u * KMUL),
                           __ATOMIC_RELAXED, __HIP_MEMORY_SCOPE_AGENT);
        __hip_atomic_store(&pairs[gp * 2 + 1], mkword((u32)(m >> 32), 1u * KMUL),
                           __ATOMIC_RELAXED, __HIP_MEMORY_SCOPE_AGENT);
    }
    __syncthreads();                        // s_bad init visible

    for (int i = 1; i < length; ++i) {
        const int par = (i - 1) & 1;
        const u32 want = (u32)i * KMUL;     // (hi^lo) of state i-1 words

        if (t == 0) {
            // pos bits of step i: x[8192+j] = (i >> (3-j)) & 1
            st[SWORDS] = ((i >> 3) & 1) | (((i >> 2) & 1) << 1) |
                         (((i >> 1) & 1) << 2) | ((i & 1) << 3);
        }
        if (t < NPAIR) {
            const u32* gsrc = (const u32*)&pairs[(par * NPAIR + t) * 2];
            // wave-uniform LDS base; builtin lands lane l at base + l*16
            volatile u32* lbase = &scr[par][(t >> 6) << 6][0];
            bool done = false;
            u32 d0 = 0xDEADBEEFu, d1 = 0xDEADBEEFu;
            if (!s_bad) {
                for (int f = 0; f < AFUSE && !done; ++f) {
                    __builtin_amdgcn_global_load_lds(
                        (const __attribute__((address_space(1))) u32*)gsrc,
                        (__attribute__((address_space(3))) u32*)lbase,
                        16, 0, 17 /* sc0|sc1 */);
                    asm volatile("s_waitcnt vmcnt(8)" ::: "memory");
                    u32 a0 = scr[par][t][0], a1 = scr[par][t][1];
                    u32 a2 = scr[par][t][2], a3 = scr[par][t][3];
                    if (((a0 ^ a1) == want) && ((a2 ^ a3) == want)) {
                        d0 = a0; d1 = a2; done = true;
                    }
                }
                if (!done) s_bad = 1;       // sticky degrade (benign race)
            }
            if (!done) {                    // proven blocking path, same words
                const u64* q = &pairs[(par * NPAIR + t) * 2];
                u64 w0, w1;
                int f = 0;
                do { w0 = __hip_atomic_load(q, __ATOMIC_RELAXED,
                                            __HIP_MEMORY_SCOPE_AGENT);
                } while ((((u32)(w0 >> 32)) ^ (u32)w0) != want && ++f < BFUSE);
                f = 0;
                do { w1 = __hip_atomic_load(q + 1, __ATOMIC_RELAXED,
                                            __HIP_MEMORY_SCOPE_AGENT);
                } while ((((u32)(w1 >> 32)) ^ (u32)w1) != want && ++f < BFUSE);
                if ((((u32)(w0 >> 32)) ^ (u32)w0) == want) d0 = (u32)w0;
                if ((((u32)(w1 >> 32)) ^ (u32)w1) == want) d1 = (u32)w1;
            }
            st[2 * t]     = d0;
            st[2 * t + 1] = d1;
        }
        __syncthreads();                    // barrier A: state i-1 complete

        // gather 10 bits -> 10-bit address (conn[0] is MSB)
        u32 addr = 0;
#pragma unroll
        for (int j = 0; j < NBT; ++j) {
            int cc = c[j];
            u32 w = st[cc >> 5];
            addr = (addr << 1) | ((w >> (cc & 31)) & 1u);
        }
        u32 pw = packedT[(n << 5) + (addr >> 5)];
        bit = (pw >> (addr & 31)) & 1;
        out[(size_t)i * BITS + n] = (float)bit;

        // publish state i (champion order: after the out-store)
        m = __ballot(bit);
        if (lane == 0) {
            const u32 tg = (u32)(i + 1) * KMUL;
            const int base = ((i & 1) * NPAIR + gp) * 2;
            __hip_atomic_store(&pairs[base],     mkword((u32)m, tg),
                               __ATOMIC_RELAXED, __HIP_MEMORY_SCOPE_AGENT);
            __hip_atomic_store(&pairs[base + 1], mkword((u32)(m >> 32), tg),
                               __ATOMIC_RELAXED, __HIP_MEMORY_SCOPE_AGENT);
        }
        __syncthreads();                    // barrier B: reads of i-1 done
    }
}

extern "C" void kernel_launch(void* const* d_in, const int* in_sizes, int n_in,
                              void* d_out, int out_size, void* d_ws, size_t ws_size,
                              hipStream_t stream) {
    const float* tm = (const float*)d_in[0];     // transition_memory [8192][1024]
    const float* im = (const float*)d_in[1];     // initial_memory    [8192][16]
    const int*   tc = (const int*)d_in[2];       // transition_connections [8192][10]
    // d_in[3] (initial_connections) is provably unused: pos_bits(0)==0 -> addr 0.
    const int length = out_size / BITS;

    u32* packed = (u32*)d_ws;                              // 1 MB
    u64* pairs  = (u64*)((char*)d_ws + (1 << 20));         // 4 KB

    // Clean mailbox every call/replay (graph-capturable memset node).
    hipMemsetAsync(pairs, 0, 2 * NPAIR * 2 * sizeof(u64), stream);

    // Pack transition RAM to bits: 8192*1024 floats, 1 thread each.
    pack_kernel<<<dim3((BITS * 1024) / 256), dim3(256), 0, stream>>>(tm, packed);

    // Persistent recurrence kernel: 16 blocks (always co-resident on 256 CUs).
    ram_step_kernel<<<dim3(NBLK), dim3(TPB), 0, stream>>>(
        tc, im, packed, pairs, (float*)d_out, length);
}